// Round 2
// baseline (322.357 us; speedup 1.0000x reference)
//
#include <hip/hip_runtime.h>
#include <math.h>

#pragma clang fp contract(off)

#define N_ROIS     1500
#define NUM_CLS    81
#define FG         80
#define SORT_N     2048
#define NMS_T      0.5f
#define SCORE_T    0.05f
#define MAX_DET    100

// float <-> order-preserving uint
__device__ __forceinline__ unsigned f2s(float f) {
    unsigned u = __float_as_uint(f);
    return (u & 0x80000000u) ? ~u : (u | 0x80000000u);
}
__device__ __forceinline__ float s2f(unsigned u) {
    return __uint_as_float((u & 0x80000000u) ? (u & 0x7FFFFFFFu) : ~u);
}

// One block per foreground class: sort scores desc (stable), decode boxes,
// greedy NMS, write sorted boxes/scores/keep + compact kept-score list.
__global__ __launch_bounds__(256) void nms_kernel(
    const float* __restrict__ rois,    // (N,5)
    const float* __restrict__ deltas,  // (N, 4*81)
    const float* __restrict__ prob,    // (N, 81)
    const float* __restrict__ iminfo,  // (1,3)
    float* __restrict__ sb,            // (80*1500, 4) sorted boxes
    float* __restrict__ ssg,           // (80*1500,)   sorted scores
    int*   __restrict__ kp,            // (80*1500,)   keep flags
    unsigned* __restrict__ compact,    // kept scores (sortable bits)
    int*   __restrict__ counter)
{
    __shared__ unsigned long long key[SORT_N];            // 16 KB
    __shared__ float ssc[N_ROIS];                         // 6 KB
    __shared__ float bx1[N_ROIS], by1[N_ROIS], bx2[N_ROIS], by2[N_ROIS], bar[N_ROIS]; // 30 KB
    __shared__ unsigned char supp[N_ROIS], keepf[N_ROIS]; // 3 KB

    const int tid = threadIdx.x;
    const int c = blockIdx.x + 1;   // class 1..80

    // --- load sort keys: score descending, index ascending (stable) ---
    for (int i = tid; i < SORT_N; i += 256) {
        if (i < N_ROIS) {
            float s = prob[i * NUM_CLS + c];
            key[i] = ((unsigned long long)(~f2s(s)) << 32) | (unsigned)i;
        } else {
            key[i] = 0xFFFFFFFFFFFFFFFFull; // pad sorts last
        }
    }

    // --- bitonic sort, ascending keys ---
    for (unsigned k = 2; k <= SORT_N; k <<= 1) {
        for (unsigned j = k >> 1; j > 0; j >>= 1) {
            __syncthreads();
            for (unsigned i = tid; i < SORT_N; i += 256) {
                unsigned ixj = i ^ j;
                if (ixj > i) {
                    unsigned long long a = key[i], b = key[ixj];
                    bool up = ((i & k) == 0);
                    if ((a > b) == up) { key[i] = b; key[ixj] = a; }
                }
            }
        }
    }
    __syncthreads();

    // --- decode boxes at sorted positions (match numpy op-for-op) ---
    const float Hm1 = iminfo[0] - 1.0f;
    const float Wm1 = iminfo[1] - 1.0f;
    for (int k = tid; k < N_ROIS; k += 256) {
        unsigned long long kk = key[k];
        int i = (int)(kk & 0xFFFFFFFFu);
        float s = s2f(~(unsigned)(kk >> 32));
        ssc[k] = s;
        const float* rp = rois + i * 5;
        float x1 = rp[1], y1 = rp[2], x2 = rp[3], y2 = rp[4];
        float w  = x2 - x1 + 1.0f;
        float h  = y2 - y1 + 1.0f;
        float cx = x1 + 0.5f * w;
        float cy = y1 + 0.5f * h;
        const float* dp = deltas + i * (4 * NUM_CLS) + c * 4;
        float dx = dp[0] / 10.0f, dy = dp[1] / 10.0f;
        float dw = dp[2] / 5.0f,  dh = dp[3] / 5.0f;
        float pcx = cx + w * dx;
        float pcy = cy + h * dy;
        float pw  = w * expf(dw);
        float ph  = h * expf(dh);
        float a1 = pcx - 0.5f * pw;
        float a2 = pcy - 0.5f * ph;
        float a3 = pcx + 0.5f * pw - 1.0f;
        float a4 = pcy + 0.5f * ph - 1.0f;
        a1 = fminf(fmaxf(a1, 0.0f), Wm1);
        a2 = fminf(fmaxf(a2, 0.0f), Hm1);
        a3 = fminf(fmaxf(a3, 0.0f), Wm1);
        a4 = fminf(fmaxf(a4, 0.0f), Hm1);
        bx1[k] = a1; by1[k] = a2; bx2[k] = a3; by2[k] = a4;
        bar[k] = (a3 - a1 + 1.0f) * (a4 - a2 + 1.0f);
        supp[k] = 0; keepf[k] = 0;
    }
    __syncthreads();

    // --- greedy NMS: sequential over sorted order, parallel suppression ---
    for (int k = 0; k < N_ROIS; ++k) {
        if (ssc[k] <= SCORE_T) break;     // uniform: sorted descending
        if (!supp[k]) {
            if (tid == 0) keepf[k] = 1;
            float x1 = bx1[k], y1 = by1[k], x2 = bx2[k], y2 = by2[k], ar = bar[k];
            for (int j = k + 1 + tid; j < N_ROIS; j += 256) {
                float iw = fminf(x2, bx2[j]) - fmaxf(x1, bx1[j]) + 1.0f;
                float ih = fminf(y2, by2[j]) - fmaxf(y1, by1[j]) + 1.0f;
                iw = fmaxf(iw, 0.0f);
                ih = fmaxf(ih, 0.0f);
                float inter = iw * ih;
                float iou = inter / ((ar + bar[j]) - inter);
                if (iou > NMS_T) supp[j] = 1;
            }
        }
        __syncthreads();
    }

    // --- write per-class outputs + compact kept scores ---
    const int base = blockIdx.x * N_ROIS;
    for (int k = tid; k < N_ROIS; k += 256) {
        int r = base + k;
        sb[r * 4 + 0] = bx1[k];
        sb[r * 4 + 1] = by1[k];
        sb[r * 4 + 2] = bx2[k];
        sb[r * 4 + 3] = by2[k];
        ssg[r] = ssc[k];
        int kv = keepf[k];
        kp[r] = kv;
        if (kv) {
            int p = atomicAdd(counter, 1);
            compact[p] = f2s(ssc[k]);
        }
    }
}

// Exact 100th-largest kept score via 32-bit MSB radix select (tie-exact,
// order-independent). Single block.
__global__ __launch_bounds__(256) void topk_kernel(
    const unsigned* __restrict__ compact,
    const int* __restrict__ counter,
    float* __restrict__ kth_out)
{
    __shared__ int red[256];
    const int tid = threadIdx.x;
    const int n = *counter;
    float kth = -INFINITY;
    if (n > MAX_DET) {
        unsigned prefix = 0;
        int kk = MAX_DET;
        for (int b = 31; b >= 0; --b) {
            int c1 = 0;
            for (int i = tid; i < n; i += 256) {
                unsigned u = compact[i];
                unsigned hi = (b == 31) ? 0u : (u >> (b + 1));
                if (hi == prefix && ((u >> b) & 1u)) c1++;
            }
            red[tid] = c1;
            __syncthreads();
            for (int s = 128; s > 0; s >>= 1) {
                if (tid < s) red[tid] += red[tid + s];
                __syncthreads();
            }
            int t = red[0];
            __syncthreads();
            if (t >= kk) prefix = (prefix << 1) | 1u;
            else { kk -= t; prefix <<= 1; }
        }
        kth = s2f(prefix);
    }
    if (tid == 0) *kth_out = kth;
}

// Emit dets (zeroed where not kept), cls_idx, keep as float32.
__global__ __launch_bounds__(256) void finalize_kernel(
    const float* __restrict__ sb,
    const float* __restrict__ ssg,
    const int*   __restrict__ kp,
    const int*   __restrict__ counter,
    const float* __restrict__ kth_ptr,
    float* __restrict__ out)
{
    const int r = blockIdx.x * 256 + threadIdx.x;
    if (r >= FG * N_ROIS) return;
    const int n = *counter;
    const float kth = *kth_ptr;
    const float s = ssg[r];
    const bool fin = (kp[r] != 0) && ((n > MAX_DET) ? (s >= kth) : true);
    float* drow = out + r * 6;
    if (fin) {
        drow[0] = 0.0f;
        drow[1] = sb[r * 4 + 0];
        drow[2] = sb[r * 4 + 1];
        drow[3] = sb[r * 4 + 2];
        drow[4] = sb[r * 4 + 3];
        drow[5] = s;
    } else {
        drow[0] = 0.0f; drow[1] = 0.0f; drow[2] = 0.0f;
        drow[3] = 0.0f; drow[4] = 0.0f; drow[5] = 0.0f;
    }
    out[FG * N_ROIS * 6 + r] = (float)(r / N_ROIS + 1);  // cls_idx
    out[FG * N_ROIS * 7 + r] = fin ? 1.0f : 0.0f;        // keep
}

extern "C" void kernel_launch(void* const* d_in, const int* in_sizes, int n_in,
                              void* d_out, int out_size, void* d_ws, size_t ws_size,
                              hipStream_t stream) {
    const float* rois   = (const float*)d_in[0];  // (1500,5)
    const float* deltas = (const float*)d_in[1];  // (1500,324)
    const float* prob   = (const float*)d_in[2];  // (1500,81)
    const float* iminfo = (const float*)d_in[3];  // (1,3)
    float* out = (float*)d_out;

    // workspace layout
    float*    sb      = (float*)d_ws;               // 480000 f
    float*    ssg     = sb + FG * N_ROIS * 4;       // 120000 f
    int*      kp      = (int*)(ssg + FG * N_ROIS);  // 120000 i
    unsigned* compact = (unsigned*)(kp + FG * N_ROIS); // 120000 u
    int*      counter = (int*)(compact + FG * N_ROIS); // 1
    float*    kth     = (float*)(counter + 1);         // 1

    hipMemsetAsync(counter, 0, sizeof(int), stream);
    nms_kernel<<<FG, 256, 0, stream>>>(rois, deltas, prob, iminfo,
                                       sb, ssg, kp, compact, counter);
    topk_kernel<<<1, 256, 0, stream>>>(compact, counter, kth);
    finalize_kernel<<<(FG * N_ROIS + 255) / 256, 256, 0, stream>>>(
        sb, ssg, kp, counter, kth, out);
}